// Round 1
// baseline (626.196 us; speedup 1.0000x reference)
//
#include <hip/hip_runtime.h>
#include <hip/hip_bf16.h>

#define NB  32
#define NTQ 1024
#define NTV 1024
#define ND  512

typedef float f32x4 __attribute__((ext_vector_type(4)));
typedef __bf16 bf16x8 __attribute__((ext_vector_type(8)));
typedef unsigned short u16x4 __attribute__((ext_vector_type(4)));
typedef unsigned short u16x8 __attribute__((ext_vector_type(8)));
typedef unsigned int u32x4 __attribute__((ext_vector_type(4)));

static __device__ __forceinline__ unsigned short f2bf(float f) {
  unsigned u = __builtin_bit_cast(unsigned, f);
  u += 0x7fffu + ((u >> 16) & 1u);          // RTN-even (inputs are finite)
  return (unsigned short)(u >> 16);
}
static __device__ __forceinline__ float bf2f(unsigned short h) {
  unsigned u = ((unsigned)h) << 16;
  return __builtin_bit_cast(float, u);
}
static __device__ __forceinline__ f32x4 mfma16(bf16x8 a, bf16x8 b, f32x4 c) {
  return __builtin_amdgcn_mfma_f32_16x16x32_bf16(a, b, c, 0, 0, 0);
}

// ---------------- kernel 0: V [B,TV,D] f32 -> Vt [B,D,TV] bf16 ----------------
__global__ __launch_bounds__(256) void k_vt(const float* __restrict__ V,
                                            unsigned short* __restrict__ Vt) {
  int vt = blockIdx.x, dt = blockIdx.y, b = blockIdx.z;
  int t = threadIdx.x;
  __shared__ unsigned short L[64][72];
#pragma unroll
  for (int r = 0; r < 4; ++r) {
    int v = (t >> 4) + r * 16;
    int c4 = (t & 15) * 4;
    f32x4 x = *(const f32x4*)(V + (size_t)(b * NTV + vt * 64 + v) * ND + dt * 64 + c4);
    u16x4 h;
#pragma unroll
    for (int j = 0; j < 4; ++j) h[j] = f2bf(x[j]);
    *(u16x4*)&L[v][c4] = h;
  }
  __syncthreads();
#pragma unroll
  for (int r = 0; r < 4; ++r) {
    int d = (t >> 4) + r * 16;
    int v4 = (t & 15) * 4;
    u16x4 o;
#pragma unroll
    for (int i = 0; i < 4; ++i) o[i] = L[v4 + i][d];
    *(u16x4*)(Vt + (size_t)(b * ND + dt * 64 + d) * NTV + vt * 64 + v4) = o;
  }
}

// ------- kernel 1: keys = V @ W^T + bias, split-bf16, packed u32 into kbuf -------
// kbuf slot (b*1024+v)*1024 + e  (aliases d_out context columns 0..511; dead until k_pv)
__global__ __launch_bounds__(256, 2) void k_keys(const float* __restrict__ V,
                                                 const float* __restrict__ W,
                                                 const float* __restrict__ bias,
                                                 unsigned int* __restrict__ kbuf) {
  int bid = blockIdx.x;
  int swz = (bid & 7) * 128 + (bid >> 3);      // XCD chunk swizzle (1024 % 8 == 0)
  int bm = swz >> 2, bn = swz & 3;
  int t = threadIdx.x, lane = t & 63, w = t >> 6;
  int wr = (w >> 1) * 64, wc = (w & 1) * 64;
  __shared__ unsigned short Ah[128][72], Al[128][72], Bh[128][72], Bl[128][72];
  f32x4 acc[4][4] = {};
  const int row0 = bm * 128, col0 = bn * 128;

  for (int k0 = 0; k0 < ND; k0 += 64) {
    __syncthreads();
#pragma unroll
    for (int r = 0; r < 8; ++r) {
      int row = (t >> 4) + r * 16;
      int c4 = (t & 15) * 4;
      f32x4 x = *(const f32x4*)(V + (size_t)(row0 + row) * ND + k0 + c4);
      u16x4 h, l;
#pragma unroll
      for (int j = 0; j < 4; ++j) {
        unsigned short hh = f2bf(x[j]);
        h[j] = hh; l[j] = f2bf(x[j] - bf2f(hh));
      }
      *(u16x4*)&Ah[row][c4] = h;
      *(u16x4*)&Al[row][c4] = l;
      f32x4 y = *(const f32x4*)(W + (size_t)(col0 + row) * ND + k0 + c4);
#pragma unroll
      for (int j = 0; j < 4; ++j) {
        unsigned short hh = f2bf(y[j]);
        h[j] = hh; l[j] = f2bf(y[j] - bf2f(hh));
      }
      *(u16x4*)&Bh[row][c4] = h;
      *(u16x4*)&Bl[row][c4] = l;
    }
    __syncthreads();
#pragma unroll
    for (int kk = 0; kk < 2; ++kk) {
      int kof = kk * 32 + ((lane >> 4) << 3);
      bf16x8 ah[4], al[4], bh[4], bl[4];
#pragma unroll
      for (int i = 0; i < 4; ++i) {
        int ra = wr + i * 16 + (lane & 15);
        ah[i] = *(const bf16x8*)&Ah[ra][kof];
        al[i] = *(const bf16x8*)&Al[ra][kof];
        int rb = wc + i * 16 + (lane & 15);
        bh[i] = *(const bf16x8*)&Bh[rb][kof];
        bl[i] = *(const bf16x8*)&Bl[rb][kof];
      }
#pragma unroll
      for (int i = 0; i < 4; ++i)
#pragma unroll
        for (int j = 0; j < 4; ++j) {
          acc[i][j] = mfma16(ah[i], bh[j], acc[i][j]);
          acc[i][j] = mfma16(ah[i], bl[j], acc[i][j]);
          acc[i][j] = mfma16(al[i], bh[j], acc[i][j]);
        }
    }
  }
#pragma unroll
  for (int j = 0; j < 4; ++j) {
    int col = col0 + wc + j * 16 + (lane & 15);
    float bj = bias[col];
#pragma unroll
    for (int i = 0; i < 4; ++i) {
      int rbase = row0 + wr + i * 16 + ((lane >> 4) << 2);
#pragma unroll
      for (int r = 0; r < 4; ++r) {
        float x = acc[i][j][r] + bj;
        unsigned short hh = f2bf(x);
        unsigned short ll = f2bf(x - bf2f(hh));
        kbuf[(size_t)(rbase + r) * (2 * ND) + col] = (unsigned)hh | ((unsigned)ll << 16);
      }
    }
  }
}

// ------- kernel 2: raw scores = Q @ keys^T, split-bf16, transposed store to out2 -------
__global__ __launch_bounds__(256, 2) void k_scores(const float* __restrict__ Q,
                                                   const unsigned int* __restrict__ kbuf,
                                                   float* __restrict__ out2) {
  int bid = blockIdx.x;
  int swz = (bid & 7) * 256 + (bid >> 3);      // 2048 % 8 == 0
  int b = swz >> 6, rr = swz & 63, vt = rr >> 3, qt = rr & 7;
  int t = threadIdx.x, lane = t & 63, w = t >> 6;
  int wr = (w >> 1) * 64, wc = (w & 1) * 64;
  __shared__ unsigned short Ah[128][72], Al[128][72], Bh[128][72], Bl[128][72];
  f32x4 acc[4][4] = {};
  const size_t qbase = (size_t)(b * NTQ + qt * 128);
  const size_t kbase = (size_t)(b * NTV + vt * 128);

  for (int k0 = 0; k0 < ND; k0 += 64) {
    __syncthreads();
#pragma unroll
    for (int r = 0; r < 8; ++r) {
      int row = (t >> 4) + r * 16;
      int c4 = (t & 15) * 4;
      f32x4 x = *(const f32x4*)(Q + (qbase + row) * ND + k0 + c4);
      u16x4 h, l;
#pragma unroll
      for (int j = 0; j < 4; ++j) {
        unsigned short hh = f2bf(x[j]);
        h[j] = hh; l[j] = f2bf(x[j] - bf2f(hh));
      }
      *(u16x4*)&Ah[row][c4] = h;
      *(u16x4*)&Al[row][c4] = l;
      u32x4 kv = *(const u32x4*)(kbuf + (kbase + row) * (2 * ND) + k0 + c4);
#pragma unroll
      for (int j = 0; j < 4; ++j) {
        h[j] = (unsigned short)(kv[j] & 0xffffu);
        l[j] = (unsigned short)(kv[j] >> 16);
      }
      *(u16x4*)&Bh[row][c4] = h;
      *(u16x4*)&Bl[row][c4] = l;
    }
    __syncthreads();
#pragma unroll
    for (int kk = 0; kk < 2; ++kk) {
      int kof = kk * 32 + ((lane >> 4) << 3);
      bf16x8 ah[4], al[4], bh[4], bl[4];
#pragma unroll
      for (int i = 0; i < 4; ++i) {
        int ra = wr + i * 16 + (lane & 15);
        ah[i] = *(const bf16x8*)&Ah[ra][kof];
        al[i] = *(const bf16x8*)&Al[ra][kof];
        int rb = wc + i * 16 + (lane & 15);
        bh[i] = *(const bf16x8*)&Bh[rb][kof];
        bl[i] = *(const bf16x8*)&Bl[rb][kof];
      }
#pragma unroll
      for (int i = 0; i < 4; ++i)
#pragma unroll
        for (int j = 0; j < 4; ++j) {
          acc[i][j] = mfma16(ah[i], bh[j], acc[i][j]);
          acc[i][j] = mfma16(ah[i], bl[j], acc[i][j]);
          acc[i][j] = mfma16(al[i], bh[j], acc[i][j]);
        }
    }
  }
  const size_t obase = (size_t)b * NTV * NTQ;
#pragma unroll
  for (int j = 0; j < 4; ++j)
#pragma unroll
    for (int i = 0; i < 4; ++i) {
      int v = vt * 128 + wc + j * 16 + (lane & 15);
      int q = qt * 128 + wr + i * 16 + ((lane >> 4) << 2);
      *(f32x4*)(out2 + obase + (size_t)v * NTQ + q) = acc[i][j];
    }
}

// ------- kernel 3: per-(b,q) online max/sum over v; also concat query into out1 -------
__global__ __launch_bounds__(128) void k_stats(const float* __restrict__ scores,
                                               const float* __restrict__ Q,
                                               float* __restrict__ out1,
                                               float2* __restrict__ stats) {
  int b = blockIdx.x >> 3, qc = blockIdx.x & 7;
  int t = threadIdx.x;
  int q = qc * 128 + t;
  const float* p = scores + (size_t)b * NTV * NTQ + q;
  float m = -3.0e38f, l = 0.f;
  for (int v = 0; v < NTV; v += 16) {
    float s[16];
#pragma unroll
    for (int i = 0; i < 16; ++i) s[i] = p[(size_t)(v + i) * NTQ];
#pragma unroll
    for (int i = 0; i < 16; ++i) {
      float mn = fmaxf(m, s[i]);
      l = l * __expf(m - mn) + __expf(s[i] - mn);
      m = mn;
    }
  }
  stats[b * NTQ + q] = make_float2(m, 1.0f / l);

  const float* qs = Q + (size_t)(b * NTQ + qc * 128) * ND;
  float* dst = out1 + (size_t)(b * NTQ + qc * 128) * (2 * ND) + ND;
  for (int i = t; i < 128 * (ND / 4); i += 128) {
    int row = i >> 7, quad = i & 127;
    *(f32x4*)(dst + (size_t)row * (2 * ND) + quad * 4) =
        *(const f32x4*)(qs + (size_t)row * ND + quad * 4);
  }
}

// ------- kernel 4: alpha = softmax (written in place to out2), context = alpha @ V -------
__global__ __launch_bounds__(512, 2) void k_pv(float* scores_align,   // out2 (in/out)
                                               const unsigned short* __restrict__ Vt,
                                               const float2* __restrict__ stats,
                                               float* __restrict__ out1) {
  int bid = blockIdx.x;
  int swz = (bid & 7) * 64 + (bid >> 3);       // 512 % 8 == 0
  int b = swz >> 4, qt = swz & 15;
  int t = threadIdx.x, lane = t & 63, w = t >> 6;
  int wq = (w >> 2) * 32, wd = (w & 3) * 128;
  int q0 = qt * 64;
  __shared__ unsigned short Asm[64][72];
  __shared__ unsigned short Bsm[512][72];
  f32x4 acc[2][8] = {};
  float mq[4], il[4];
  int vb = t & 15, qb = t >> 4;                // used for t < 256
  if (t < 256) {
#pragma unroll
    for (int j = 0; j < 4; ++j) {
      float2 st = stats[b * NTQ + q0 + qb * 4 + j];
      mq[j] = st.x; il[j] = st.y;
    }
  }
  const size_t sbase = (size_t)b * NTV * NTQ;

  for (int v0 = 0; v0 < NTV; v0 += 64) {
    __syncthreads();
    if (t < 256) {
      f32x4 rows[4];
#pragma unroll
      for (int i = 0; i < 4; ++i) {
        size_t ofs = sbase + (size_t)(v0 + vb * 4 + i) * NTQ + q0 + qb * 4;
        rows[i] = *(const f32x4*)(scores_align + ofs);
#pragma unroll
        for (int j = 0; j < 4; ++j) rows[i][j] = __expf(rows[i][j] - mq[j]) * il[j];
        *(f32x4*)(scores_align + ofs) = rows[i];   // normalized alignment (output)
      }
#pragma unroll
      for (int j = 0; j < 4; ++j) {                // 4x4 register transpose -> LDS [q][v]
        u16x4 col;
#pragma unroll
        for (int i = 0; i < 4; ++i) col[i] = f2bf(rows[i][j]);
        *(u16x4*)&Asm[qb * 4 + j][vb * 4] = col;
      }
    }
#pragma unroll
    for (int rr = 0; rr < 8; ++rr) {
      int d = (t >> 3) + rr * 64;
      int c8 = (t & 7) * 8;
      *(u16x8*)&Bsm[d][c8] =
          *(const u16x8*)(Vt + (size_t)(b * ND + d) * NTV + v0 + c8);
    }
    __syncthreads();
#pragma unroll
    for (int kk = 0; kk < 2; ++kk) {
      int kof = kk * 32 + ((lane >> 4) << 3);
      bf16x8 af[2], bfr[8];
#pragma unroll
      for (int i = 0; i < 2; ++i)
        af[i] = *(const bf16x8*)&Asm[wq + i * 16 + (lane & 15)][kof];
#pragma unroll
      for (int j = 0; j < 8; ++j)
        bfr[j] = *(const bf16x8*)&Bsm[wd + j * 16 + (lane & 15)][kof];
#pragma unroll
      for (int i = 0; i < 2; ++i)
#pragma unroll
        for (int j = 0; j < 8; ++j) acc[i][j] = mfma16(af[i], bfr[j], acc[i][j]);
    }
  }
#pragma unroll
  for (int i = 0; i < 2; ++i)
#pragma unroll
    for (int j = 0; j < 8; ++j)
#pragma unroll
      for (int rr = 0; rr < 4; ++rr) {
        int q = q0 + wq + i * 16 + ((lane >> 4) << 2) + rr;
        int d = wd + j * 16 + (lane & 15);
        out1[(size_t)(b * NTQ + q) * (2 * ND) + d] = acc[i][j][rr];
      }
}

extern "C" void kernel_launch(void* const* d_in, const int* in_sizes, int n_in,
                              void* d_out, int out_size, void* d_ws, size_t ws_size,
                              hipStream_t stream) {
  const float* Q    = (const float*)d_in[0];   // [B,TQ,D]
  const float* V    = (const float*)d_in[1];   // [B,TV,D]
  const float* W    = (const float*)d_in[2];   // [D,D]
  const float* bias = (const float*)d_in[3];   // [D]

  float* out1 = (float*)d_out;                                   // context_cat [B,TQ,2D]
  float* out2 = (float*)d_out + (size_t)NB * NTQ * (2 * ND);     // alignment_t [B,TV,TQ]

  // ws: Vt bf16 [B,D,TV] (32 MiB) + stats float2 [B*TQ] (256 KiB)
  unsigned short* Vt = (unsigned short*)d_ws;
  float2* stats = (float2*)(Vt + (size_t)NB * ND * NTV);

  // keys (hi|lo packed u32) live temporarily in out1's context columns (overwritten by k_pv)
  unsigned int* kbuf = (unsigned int*)out1;

  k_vt<<<dim3(16, 8, 32), 256, 0, stream>>>(V, Vt);
  k_keys<<<1024, 256, 0, stream>>>(V, W, bias, kbuf);
  k_scores<<<2048, 256, 0, stream>>>(Q, kbuf, out2);
  k_stats<<<256, 128, 0, stream>>>(out2, Q, out1, stats);
  k_pv<<<512, 512, 0, stream>>>(out2, Vt, stats, out1);
}

// Round 3
// 488.675 us; speedup vs baseline: 1.2814x; 1.2814x over previous
//
#include <hip/hip_runtime.h>
#include <hip/hip_bf16.h>

#define NB  32
#define NTQ 1024
#define NTV 1024
#define ND  512

typedef float f32x4 __attribute__((ext_vector_type(4)));
typedef float f32x2 __attribute__((ext_vector_type(2)));
typedef __bf16 bf16x8 __attribute__((ext_vector_type(8)));
typedef unsigned short u16x4 __attribute__((ext_vector_type(4)));
typedef unsigned short u16x8 __attribute__((ext_vector_type(8)));
typedef unsigned int u32x2 __attribute__((ext_vector_type(2)));
typedef unsigned int u32x4 __attribute__((ext_vector_type(4)));

static __device__ __forceinline__ unsigned short f2bf(float f) {   // RTN-even
  unsigned u = __builtin_bit_cast(unsigned, f);
  u += 0x7fffu + ((u >> 16) & 1u);
  return (unsigned short)(u >> 16);
}
// trunc split: returns packed (hi | lo<<16); x = hi + lo exactly at fp32 before lo-trunc
static __device__ __forceinline__ unsigned split2(float x) {
  unsigned u = __builtin_bit_cast(unsigned, x);
  unsigned h = u >> 16;
  float hf = __builtin_bit_cast(float, u & 0xffff0000u);
  unsigned l = __builtin_bit_cast(unsigned, x - hf) >> 16;
  return h | (l << 16);
}
static __device__ __forceinline__ f32x4 mfma16(bf16x8 a, bf16x8 b, f32x4 c) {
  return __builtin_amdgcn_mfma_f32_16x16x32_bf16(a, b, c, 0, 0, 0);
}

// ---------------- kernel 0: V [B,TV,D] f32 -> Vt [B,D,TV] bf16 ----------------
__global__ __launch_bounds__(256) void k_vt(const float* __restrict__ V,
                                            unsigned short* __restrict__ Vt) {
  int vt = blockIdx.x, dt = blockIdx.y, b = blockIdx.z;
  int t = threadIdx.x;
  __shared__ unsigned short L[64][72];
#pragma unroll
  for (int r = 0; r < 4; ++r) {
    int v = (t >> 4) + r * 16;
    int c4 = (t & 15) * 4;
    f32x4 x = *(const f32x4*)(V + (size_t)(b * NTV + vt * 64 + v) * ND + dt * 64 + c4);
    u16x4 h;
#pragma unroll
    for (int j = 0; j < 4; ++j) h[j] = f2bf(x[j]);
    *(u16x4*)&L[v][c4] = h;
  }
  __syncthreads();
#pragma unroll
  for (int r = 0; r < 4; ++r) {
    int d = (t >> 4) + r * 16;
    int v4 = (t & 15) * 4;
    u16x4 o;
#pragma unroll
    for (int i = 0; i < 4; ++i) o[i] = L[v4 + i][d];
    *(u16x4*)(Vt + (size_t)(b * ND + dt * 64 + d) * NTV + vt * 64 + v4) = o;
  }
}

// ------- kernel 1: keys = V @ W^T + bias, trunc-split bf16, packed u32 into kbuf -------
__global__ __launch_bounds__(256, 2) void k_keys(const float* __restrict__ V,
                                                 const float* __restrict__ W,
                                                 const float* __restrict__ bias,
                                                 unsigned int* __restrict__ kbuf) {
  int bid = blockIdx.x;
  int swz = (bid & 7) * 128 + (bid >> 3);
  int bm = swz >> 2, bn = swz & 3;
  int t = threadIdx.x, lane = t & 63, w = t >> 6;
  int wr = (w >> 1) * 64, wc = (w & 1) * 64;
  __shared__ __align__(16) unsigned char SMEM[73728];
  unsigned short (*Ah)[72] = (unsigned short(*)[72])(SMEM);
  unsigned short (*Al)[72] = (unsigned short(*)[72])(SMEM + 18432);
  unsigned short (*Bh)[72] = (unsigned short(*)[72])(SMEM + 36864);
  unsigned short (*Bl)[72] = (unsigned short(*)[72])(SMEM + 55296);
  f32x4 acc[4][4] = {};
  const int row0 = bm * 128, col0 = bn * 128;

  for (int k0 = 0; k0 < ND; k0 += 64) {
    __syncthreads();
#pragma unroll
    for (int r = 0; r < 8; ++r) {
      int row = (t >> 4) + r * 16;
      int c4 = (t & 15) * 4;
      f32x4 x = *(const f32x4*)(V + (size_t)(row0 + row) * ND + k0 + c4);
      u16x4 h, l;
#pragma unroll
      for (int j = 0; j < 4; ++j) {
        unsigned p = split2(x[j]);
        h[j] = (unsigned short)(p & 0xffffu);
        l[j] = (unsigned short)(p >> 16);
      }
      *(u16x4*)&Ah[row][c4] = h;
      *(u16x4*)&Al[row][c4] = l;
      f32x4 y = *(const f32x4*)(W + (size_t)(col0 + row) * ND + k0 + c4);
#pragma unroll
      for (int j = 0; j < 4; ++j) {
        unsigned p = split2(y[j]);
        h[j] = (unsigned short)(p & 0xffffu);
        l[j] = (unsigned short)(p >> 16);
      }
      *(u16x4*)&Bh[row][c4] = h;
      *(u16x4*)&Bl[row][c4] = l;
    }
    __syncthreads();
#pragma unroll
    for (int kk = 0; kk < 2; ++kk) {
      int kof = kk * 32 + ((lane >> 4) << 3);
      bf16x8 ah[4], al[4], bh[4], bl[4];
#pragma unroll
      for (int i = 0; i < 4; ++i) {
        int ra = wr + i * 16 + (lane & 15);
        ah[i] = *(const bf16x8*)&Ah[ra][kof];
        al[i] = *(const bf16x8*)&Al[ra][kof];
        int rb = wc + i * 16 + (lane & 15);
        bh[i] = *(const bf16x8*)&Bh[rb][kof];
        bl[i] = *(const bf16x8*)&Bl[rb][kof];
      }
#pragma unroll
      for (int i = 0; i < 4; ++i)
#pragma unroll
        for (int j = 0; j < 4; ++j) {
          acc[i][j] = mfma16(ah[i], bh[j], acc[i][j]);
          acc[i][j] = mfma16(ah[i], bl[j], acc[i][j]);
          acc[i][j] = mfma16(al[i], bh[j], acc[i][j]);
        }
    }
  }
  // ---- epilogue: stage packed C-tile in LDS (pitch 134 u32), then coalesced writes ----
  __syncthreads();
  unsigned* CT = (unsigned*)SMEM;                    // 128 x 134 u32 = 68608 B
#pragma unroll
  for (int j = 0; j < 4; ++j) {
    int col_l = wc + j * 16 + (lane & 15);
    float bj = bias[col0 + col_l];
#pragma unroll
    for (int i = 0; i < 4; ++i) {
      int rb_l = wr + i * 16 + ((lane >> 4) << 2);
#pragma unroll
      for (int r = 0; r < 4; ++r) {
        CT[(rb_l + r) * 134 + col_l] = split2(acc[i][j][r] + bj);
      }
    }
  }
  __syncthreads();
#pragma unroll
  for (int it = 0; it < 32; ++it) {
    int idx = it * 256 + t;          // 8192 u32x2 chunks
    int row = idx >> 6, c2 = idx & 63;
    *(u32x2*)(kbuf + (size_t)(row0 + row) * 1024 + col0 + c2 * 2) =
        *(const u32x2*)&CT[row * 134 + c2 * 2];
  }
}

// ------- kernel 2: raw scores = Q @ keys^T, trunc-split, transposed coalesced store -------
__global__ __launch_bounds__(256, 2) void k_scores(const float* __restrict__ Q,
                                                   const unsigned int* __restrict__ kbuf,
                                                   float* __restrict__ out2) {
  int bid = blockIdx.x;
  int swz = (bid & 7) * 256 + (bid >> 3);
  int b = swz >> 6, rr = swz & 63, vt = rr >> 3, qt = rr & 7;
  int t = threadIdx.x, lane = t & 63, w = t >> 6;
  int wr = (w >> 1) * 64, wc = (w & 1) * 64;
  __shared__ __align__(16) unsigned char SMEM[73728];
  unsigned short (*Ah)[72] = (unsigned short(*)[72])(SMEM);
  unsigned short (*Al)[72] = (unsigned short(*)[72])(SMEM + 18432);
  unsigned short (*Bh)[72] = (unsigned short(*)[72])(SMEM + 36864);
  unsigned short (*Bl)[72] = (unsigned short(*)[72])(SMEM + 55296);
  f32x4 acc[4][4] = {};
  const size_t qbase = (size_t)(b * NTQ + qt * 128);
  const size_t kbase = (size_t)(b * NTV + vt * 128);

  for (int k0 = 0; k0 < ND; k0 += 64) {
    __syncthreads();
#pragma unroll
    for (int r = 0; r < 8; ++r) {
      int row = (t >> 4) + r * 16;
      int c4 = (t & 15) * 4;
      f32x4 x = *(const f32x4*)(Q + (qbase + row) * ND + k0 + c4);
      u16x4 h, l;
#pragma unroll
      for (int j = 0; j < 4; ++j) {
        unsigned p = split2(x[j]);
        h[j] = (unsigned short)(p & 0xffffu);
        l[j] = (unsigned short)(p >> 16);
      }
      *(u16x4*)&Ah[row][c4] = h;
      *(u16x4*)&Al[row][c4] = l;
      u32x4 kv = *(const u32x4*)(kbuf + (kbase + row) * (2 * ND) + k0 + c4);
#pragma unroll
      for (int j = 0; j < 4; ++j) {
        h[j] = (unsigned short)(kv[j] & 0xffffu);
        l[j] = (unsigned short)(kv[j] >> 16);
      }
      *(u16x4*)&Bh[row][c4] = h;
      *(u16x4*)&Bl[row][c4] = l;
    }
    __syncthreads();
#pragma unroll
    for (int kk = 0; kk < 2; ++kk) {
      int kof = kk * 32 + ((lane >> 4) << 3);
      bf16x8 ah[4], al[4], bh[4], bl[4];
#pragma unroll
      for (int i = 0; i < 4; ++i) {
        int ra = wr + i * 16 + (lane & 15);
        ah[i] = *(const bf16x8*)&Ah[ra][kof];
        al[i] = *(const bf16x8*)&Al[ra][kof];
        int rb = wc + i * 16 + (lane & 15);
        bh[i] = *(const bf16x8*)&Bh[rb][kof];
        bl[i] = *(const bf16x8*)&Bl[rb][kof];
      }
#pragma unroll
      for (int i = 0; i < 4; ++i)
#pragma unroll
        for (int j = 0; j < 4; ++j) {
          acc[i][j] = mfma16(ah[i], bh[j], acc[i][j]);
          acc[i][j] = mfma16(ah[i], bl[j], acc[i][j]);
          acc[i][j] = mfma16(al[i], bh[j], acc[i][j]);
        }
    }
  }
  // ---- epilogue: transpose tile into LDS [v][q] (pitch 134 f32), coalesced row writes ----
  __syncthreads();
  float* CT = (float*)SMEM;                          // 128 x 134 f32 = 68608 B
#pragma unroll
  for (int j = 0; j < 4; ++j)
#pragma unroll
    for (int i = 0; i < 4; ++i) {
      int v_l = wc + j * 16 + (lane & 15);
      int q_l = wr + i * 16 + ((lane >> 4) << 2);
#pragma unroll
      for (int r = 0; r < 4; ++r) CT[v_l * 134 + q_l + r] = acc[i][j][r];
    }
  __syncthreads();
  const size_t obase = (size_t)b * NTV * NTQ;
#pragma unroll
  for (int it = 0; it < 32; ++it) {
    int idx = it * 256 + t;
    int row = idx >> 6, c2 = idx & 63;
    *(f32x2*)(out2 + obase + (size_t)(vt * 128 + row) * NTQ + qt * 128 + c2 * 2) =
        *(const f32x2*)&CT[row * 134 + c2 * 2];
  }
}

// ------- kernel 3: per-(b,q) max/sum over v (4-way v-split); concat query into out1 -------
__global__ __launch_bounds__(256) void k_stats(const float* __restrict__ scores,
                                               const float* __restrict__ Q,
                                               float* __restrict__ out1,
                                               float2* __restrict__ stats) {
  int b = blockIdx.x >> 4, qc = blockIdx.x & 15;
  int t = threadIdx.x;
  int ql = t & 63, vs = t >> 6;
  int q = qc * 64 + ql;
  const float* p = scores + (size_t)b * NTV * NTQ + (size_t)(vs * 256) * NTQ + q;
  float m = -3.0e38f, l = 0.f;
  for (int v = 0; v < 256; v += 16) {
    float s[16];
#pragma unroll
    for (int i = 0; i < 16; ++i) s[i] = p[(size_t)(v + i) * NTQ];
#pragma unroll
    for (int i = 0; i < 16; ++i) {
      float mn = fmaxf(m, s[i]);
      l = l * __expf(m - mn) + __expf(s[i] - mn);
      m = mn;
    }
  }
  __shared__ float2 part[4][64];
  part[vs][ql] = make_float2(m, l);
  __syncthreads();
  if (t < 64) {
    float2 a = part[0][t], b2 = part[1][t], c = part[2][t], d = part[3][t];
    float mm = fmaxf(fmaxf(a.x, b2.x), fmaxf(c.x, d.x));
    float ll = a.y * __expf(a.x - mm) + b2.y * __expf(b2.x - mm) +
               c.y * __expf(c.x - mm) + d.y * __expf(d.x - mm);
    stats[b * NTQ + qc * 64 + t] = make_float2(mm, 1.0f / ll);
  }
  const float* qs = Q + (size_t)(b * NTQ + qc * 64) * ND;
  float* dst = out1 + (size_t)(b * NTQ + qc * 64) * (2 * ND) + ND;
  for (int i = t; i < 64 * (ND / 4); i += 256) {
    int row = i >> 7, quad = i & 127;
    *(f32x4*)(dst + (size_t)row * (2 * ND) + quad * 4) =
        *(const f32x4*)(qs + (size_t)row * ND + quad * 4);
  }
}

// ------- kernel 4: alpha = softmax (in place via LDS, coalesced), context = alpha @ V -------
__global__ __launch_bounds__(512, 1) void k_pv(float* scores_align,
                                               const unsigned short* __restrict__ Vt,
                                               const float2* __restrict__ stats,
                                               float* __restrict__ out1) {
  int bid = blockIdx.x;
  int swz = (bid & 7) * 64 + (bid >> 3);
  int b = swz >> 4, qt = swz & 15;
  int t = threadIdx.x, lane = t & 63, w = t >> 6;
  int wq = (w >> 2) * 32, wd = (w & 3) * 128;
  int q0 = qt * 64;
  __shared__ __align__(16) unsigned char SMEM[100352];
  unsigned short (*Asm)[72] = (unsigned short(*)[72])(SMEM);            // 64x72 u16
  unsigned short (*Bsm)[72] = (unsigned short(*)[72])(SMEM + 9216);     // 512x72 u16
  float (*SF)[68] = (float(*)[68])(SMEM + 9216 + 73728);                // 64x68 f32
  float* CT = (float*)(SMEM + 9216);                                    // epilogue alias

  f32x4 acc[2][8] = {};
  float mq[4], il[4];
  int vb = t & 15, qb = t >> 4;   // for t < 256
  if (t < 256) {
#pragma unroll
    for (int j = 0; j < 4; ++j) {
      float2 st = stats[b * NTQ + q0 + qb * 4 + j];
      mq[j] = st.x; il[j] = st.y;
    }
  }
  const size_t sbase = (size_t)b * NTV * NTQ;

  for (int v0 = 0; v0 < NTV; v0 += 64) {
    __syncthreads();
    // 1) stage V-tile (all 512 threads)
#pragma unroll
    for (int rr = 0; rr < 8; ++rr) {
      int d = (t >> 3) + rr * 64;
      int c8 = (t & 7) * 8;
      *(u16x8*)&Bsm[d][c8] = *(const u16x8*)(Vt + (size_t)(b * ND + d) * NTV + v0 + c8);
    }
    // 2) stage raw-score tile global -> SF (256B runs)
#pragma unroll
    for (int ps = 0; ps < 2; ++ps) {
      int idx = ps * 512 + t;
      int row = idx >> 4, ch = idx & 15;
      *(f32x4*)&SF[row][ch * 4] =
          *(const f32x4*)(scores_align + sbase + (size_t)(v0 + row) * NTQ + q0 + ch * 4);
    }
    __syncthreads();
    // 3) exp + normalize in LDS; build bf16 A-tile [q][v]
    if (t < 256) {
      f32x4 rows_[4];
#pragma unroll
      for (int i = 0; i < 4; ++i) {
        f32x4 x = *(const f32x4*)&SF[vb * 4 + i][qb * 4];
#pragma unroll
        for (int j = 0; j < 4; ++j) x[j] = __expf(x[j] - mq[j]) * il[j];
        *(f32x4*)&SF[vb * 4 + i][qb * 4] = x;
        rows_[i] = x;
      }
#pragma unroll
      for (int j = 0; j < 4; ++j) {
        u16x4 col;
#pragma unroll
        for (int i = 0; i < 4; ++i) col[i] = f2bf(rows_[i][j]);
        *(u16x4*)&Asm[qb * 4 + j][vb * 4] = col;
      }
    }
    __syncthreads();
    // 4) write alpha back (256B runs), overlapped with MFMA
#pragma unroll
    for (int ps = 0; ps < 2; ++ps) {
      int idx = ps * 512 + t;
      int row = idx >> 4, ch = idx & 15;
      *(f32x4*)(scores_align + sbase + (size_t)(v0 + row) * NTQ + q0 + ch * 4) =
          *(const f32x4*)&SF[row][ch * 4];
    }
#pragma unroll
    for (int kk = 0; kk < 2; ++kk) {
      int kof = kk * 32 + ((lane >> 4) << 3);
      bf16x8 af[2], bfr[8];
#pragma unroll
      for (int i = 0; i < 2; ++i)
        af[i] = *(const bf16x8*)&Asm[wq + i * 16 + (lane & 15)][kof];
#pragma unroll
      for (int j = 0; j < 8; ++j)
        bfr[j] = *(const bf16x8*)&Bsm[wd + j * 16 + (lane & 15)][kof];
#pragma unroll
      for (int i = 0; i < 2; ++i)
#pragma unroll
        for (int j = 0; j < 8; ++j) acc[i][j] = mfma16(af[i], bfr[j], acc[i][j]);
    }
  }
  // ---- epilogue: context via LDS staging (pitch 260), two d-halves, 512B runs ----
#pragma unroll
  for (int h = 0; h < 2; ++h) {
    __syncthreads();
    if (((w & 3) >> 1) == h) {
      int dbase = wd - h * 256;
#pragma unroll
      for (int i = 0; i < 2; ++i)
#pragma unroll
        for (int j = 0; j < 8; ++j) {
          int q_l = wq + i * 16 + ((lane >> 4) << 2);
          int d_l = dbase + j * 16 + (lane & 15);
#pragma unroll
          for (int r = 0; r < 4; ++r) CT[(q_l + r) * 260 + d_l] = acc[i][j][r];
        }
    }
    __syncthreads();
#pragma unroll
    for (int it = 0; it < 16; ++it) {
      int idx = it * 512 + t;
      int row = idx >> 7, c2 = idx & 127;
      *(f32x2*)(out1 + (size_t)(b * NTQ + q0 + row) * (2 * ND) + h * 256 + c2 * 2) =
          *(const f32x2*)&CT[row * 260 + c2 * 2];
    }
  }
}

extern "C" void kernel_launch(void* const* d_in, const int* in_sizes, int n_in,
                              void* d_out, int out_size, void* d_ws, size_t ws_size,
                              hipStream_t stream) {
  const float* Q    = (const float*)d_in[0];
  const float* V    = (const float*)d_in[1];
  const float* W    = (const float*)d_in[2];
  const float* bias = (const float*)d_in[3];

  float* out1 = (float*)d_out;                                   // context_cat [B,TQ,2D]
  float* out2 = (float*)d_out + (size_t)NB * NTQ * (2 * ND);     // alignment_t [B,TV,TQ]

  unsigned short* Vt = (unsigned short*)d_ws;                    // bf16 [B,D,TV]
  float2* stats = (float2*)(Vt + (size_t)NB * ND * NTV);

  unsigned int* kbuf = (unsigned int*)out1;                      // keys hi|lo packed (temp)

  k_vt<<<dim3(16, 8, 32), 256, 0, stream>>>(V, Vt);
  k_keys<<<1024, 256, 0, stream>>>(V, W, bias, kbuf);
  k_scores<<<2048, 256, 0, stream>>>(Q, kbuf, out2);
  k_stats<<<512, 256, 0, stream>>>(out2, Q, out1, stats);
  k_pv<<<512, 512, 0, stream>>>(out2, Vt, stats, out1);
}